// Round 1
// baseline (39.681 us; speedup 1.0000x reference)
//
#include <hip/hip_runtime.h>

// out[b,s,h,w] = sum_t input[b,s,t,h,w] * weight[t, h%8, w%8]   (h,w < 256; else 0)
// output[b, s*1024 + i*32 + j, q*16 + p] = out[b,s, 8i+p, 8j+q]   i,j in [0,32), p,q in [0,16)
//
// Block = (b, s, ig, jg): windows i in [4*ig, 4*ig+4), j in [16*jg, 16*jg+16).
// Needs out region rows [32*ig, 32*ig+40) x cols [128*jg, 128*jg+136).
// Phase 1: compute region into LDS (coalesced float4 input loads).
// Phase 2: write 64 windows as coalesced float4 stores from LDS.

namespace {

constexpr int TT   = 16;
constexpr int ROWS = 40;   // 4*8 + 8 halo
constexpr int C4   = 34;   // float4 slots per row = 136 cols
constexpr int LDSW = 140;  // row pitch (floats): 140*4B = 35*16B -> float4-aligned rows, odd/32 bank spread

__global__ __launch_bounds__(256) void meas_kernel(
    const float* __restrict__ in, const float* __restrict__ wt,
    float* __restrict__ out)
{
    __shared__ float tile[ROWS * LDSW];
    __shared__ float wlds[TT * 64];

    const int tid = threadIdx.x;
    for (int idx = tid; idx < TT * 64; idx += 256) wlds[idx] = wt[idx];

    const int bid = blockIdx.x;
    const int jg = bid & 1;
    const int ig = (bid >> 1) & 7;
    const int s  = (bid >> 4) & 3;
    const int b  = bid >> 6;

    const int i0 = ig * 4;    // first window row
    const int j0 = jg * 16;   // first window col
    const int h0 = i0 * 8;    // region row origin
    const int w0 = j0 * 8;    // region col origin (0 or 128)

    const float* __restrict__ inp = in + (size_t)(b * 4 + s) * TT * 65536;

    __syncthreads();

    // ---- Phase 1: compute 40 x 136 region into LDS ----
    for (int slot = tid; slot < ROWS * C4; slot += 256) {
        const int r  = slot / C4;
        const int c4 = slot - r * C4;
        const int h  = h0 + r;
        const int w  = w0 + c4 * 4;
        float4 acc = make_float4(0.f, 0.f, 0.f, 0.f);
        if (h < 256 && w < 256) {
            // w is a multiple of 4, so w..w+3 stay inside one mod-8 group
            const float* wrow = &wlds[(h & 7) * 8 + (w & 7)];
            const float* gp   = inp + h * 256 + w;
#pragma unroll
            for (int t = 0; t < TT; ++t) {
                const float4 v = *reinterpret_cast<const float4*>(gp + t * 65536);
                const float* wr = wrow + t * 64;
                acc.x += v.x * wr[0];
                acc.y += v.y * wr[1];
                acc.z += v.z * wr[2];
                acc.w += v.w * wr[3];
            }
        }
        *reinterpret_cast<float4*>(&tile[r * LDSW + c4 * 4]) = acc;
    }

    __syncthreads();

    // ---- Phase 2: emit 64 windows (4 x 16), coalesced float4 stores ----
    // output element k = 4*lane + jj : p = 4*(lane%4) + jj, q = lane/4
    const int wave = tid >> 6;
    const int lane = tid & 63;
    const int p0 = (lane & 3) * 4;
    const int q  = lane >> 2;
    float* __restrict__ outb = out + ((size_t)b * 4096 + (size_t)s * 1024) * 256;

    for (int widx = wave; widx < 64; widx += 4) {
        const int di = widx >> 4;   // 0..3
        const int dj = widx & 15;   // 0..15
        const float* src = &tile[(di * 8 + p0) * LDSW + dj * 8 + q];
        float4 v;
        v.x = src[0 * LDSW];
        v.y = src[1 * LDSW];
        v.z = src[2 * LDSW];
        v.w = src[3 * LDSW];
        const int n = (i0 + di) * 32 + (j0 + dj);
        *reinterpret_cast<float4*>(outb + (size_t)n * 256 + lane * 4) = v;
    }
}

} // namespace

extern "C" void kernel_launch(void* const* d_in, const int* in_sizes, int n_in,
                              void* d_out, int out_size, void* d_ws, size_t ws_size,
                              hipStream_t stream) {
    const float* in = (const float*)d_in[0];
    const float* wt = (const float*)d_in[1];
    float* out      = (float*)d_out;
    hipLaunchKernelGGL(meas_kernel, dim3(512), dim3(256), 0, stream, in, wt, out);
}

// Round 2
// 38.004 us; speedup vs baseline: 1.0441x; 1.0441x over previous
//
#include <hip/hip_runtime.h>

// out[b,s,h,w] = sum_t input[b,s,t,h,w] * weight[t, h%8, w%8]   (h,w < 256; else 0)
// output[b, s*1024 + i*32 + j, q*16 + p] = out[b,s, 8i+p, 8j+q]   i,j in [0,32), p,q in [0,16)
//
// Block = (b, s, ig, jg): windows i in [4*ig, 4*ig+4), j in [16*jg, 16*jg+16).
// Needs out region rows [32*ig, 32*ig+40) x cols [128*jg, 128*jg+136).
// Phase 1: compute region into LDS (coalesced float4 input loads, float4 weight reads).
// Phase 2: write 64 windows as coalesced float4 stores from LDS.
//
// 512 threads/block, grid 512 -> 2 blocks/CU, 16 waves/CU (was 8: latency-bound).
// XCD swizzle: 64 consecutive logical blocks (= one batch image) per XCD for halo L2 reuse.

namespace {

constexpr int TT   = 16;
constexpr int ROWS = 40;   // 4*8 + 8 halo
constexpr int C4   = 34;   // float4 slots per row = 136 cols
constexpr int LDSW = 140;  // row pitch (floats): float4-aligned rows, odd/32 bank spread

__global__ __launch_bounds__(512, 4) void meas_kernel(
    const float* __restrict__ in, const float* __restrict__ wt,
    float* __restrict__ out)
{
    __shared__ float tile[ROWS * LDSW];
    __shared__ float wlds[TT * 64];

    const int tid = threadIdx.x;
    for (int idx = tid; idx < TT * 64; idx += 512) wlds[idx] = wt[idx];

    // XCD-aware swizzle: 512 blocks, 8 XCDs -> 64 logical blocks per XCD.
    // Logical id bits: b(6..8) | s(4..5) | ig(1..3) | jg(0); chunk of 64 = one b.
    const int bid = (blockIdx.x & 7) * 64 + (blockIdx.x >> 3);
    const int jg = bid & 1;
    const int ig = (bid >> 1) & 7;
    const int s  = (bid >> 4) & 3;
    const int b  = bid >> 6;

    const int i0 = ig * 4;    // first window row
    const int j0 = jg * 16;   // first window col
    const int h0 = i0 * 8;    // region row origin
    const int w0 = j0 * 8;    // region col origin (0 or 128)

    const float* __restrict__ inp = in + (size_t)(b * 4 + s) * TT * 65536;

    __syncthreads();

    // ---- Phase 1: compute 40 x 136 region into LDS ----
    for (int slot = tid; slot < ROWS * C4; slot += 512) {
        const int r  = slot / C4;
        const int c4 = slot - r * C4;
        const int h  = h0 + r;
        const int w  = w0 + c4 * 4;
        float4 acc = make_float4(0.f, 0.f, 0.f, 0.f);
        if (h < 256 && w < 256) {
            // w is a multiple of 4, so w..w+3 stay inside one mod-8 group,
            // and (h&7)*8 + (w&7) is 4-aligned -> float4 weight reads.
            const float* wrow = &wlds[(h & 7) * 8 + (w & 7)];
            const float* gp   = inp + h * 256 + w;
#pragma unroll
            for (int t = 0; t < TT; ++t) {
                const float4 v  = *reinterpret_cast<const float4*>(gp + t * 65536);
                const float4 wv = *reinterpret_cast<const float4*>(wrow + t * 64);
                acc.x += v.x * wv.x;
                acc.y += v.y * wv.y;
                acc.z += v.z * wv.z;
                acc.w += v.w * wv.w;
            }
        }
        *reinterpret_cast<float4*>(&tile[r * LDSW + c4 * 4]) = acc;
    }

    __syncthreads();

    // ---- Phase 2: emit 64 windows (4 x 16), coalesced float4 stores ----
    // output element k = 4*lane + jj : p = 4*(lane%4) + jj, q = lane/4
    const int wave = tid >> 6;     // 0..7
    const int lane = tid & 63;
    const int p0 = (lane & 3) * 4;
    const int q  = lane >> 2;
    float* __restrict__ outb = out + ((size_t)b * 4096 + (size_t)s * 1024) * 256;

    for (int widx = wave; widx < 64; widx += 8) {
        const int di = widx >> 4;   // 0..3
        const int dj = widx & 15;   // 0..15
        const float* src = &tile[(di * 8 + p0) * LDSW + dj * 8 + q];
        float4 v;
        v.x = src[0 * LDSW];
        v.y = src[1 * LDSW];
        v.z = src[2 * LDSW];
        v.w = src[3 * LDSW];
        const int n = (i0 + di) * 32 + (j0 + dj);
        *reinterpret_cast<float4*>(outb + (size_t)n * 256 + lane * 4) = v;
    }
}

} // namespace

extern "C" void kernel_launch(void* const* d_in, const int* in_sizes, int n_in,
                              void* d_out, int out_size, void* d_ws, size_t ws_size,
                              hipStream_t stream) {
    const float* in = (const float*)d_in[0];
    const float* wt = (const float*)d_in[1];
    float* out      = (float*)d_out;
    hipLaunchKernelGGL(meas_kernel, dim3(512), dim3(512), 0, stream, in, wt, out);
}

// Round 4
// 37.576 us; speedup vs baseline: 1.0560x; 1.0114x over previous
//
#include <hip/hip_runtime.h>

// out[b,s,h,w] = sum_t input[b,s,t,h,w] * weight[t, h%8, w%8]   (h,w < 256; else 0)
// output[b, s*1024 + i*32 + j, q*16 + p] = out[b,s, 8i+p, 8j+q]   i,j in [0,32), p,q in [0,16)
//
// Block = (b, s, ig, jg): windows i in [4*ig, 4*ig+4), j in [16*jg, 16*jg+16).
// Region rows [32*ig, 32*ig+40) x cols [128*jg, 128*jg+136).
//
// Software pipeline to overlap output writes with input reads (round-2 post-mortem:
// T_read(33us) + T_write(5us) were fully serialized):
//   P1a: compute tile rows [0,24) -> LDS
//   bar
//   P1b: issue loads+FMA for rows [24,40) (accs in regs, LDS commit deferred)
//   S01: store windows di=0,1 (reads LDS rows 0..23) -- overlaps P1b's in-flight loads
//   commit P1b accs to LDS
//   bar
//   S23: store windows di=2,3

namespace {

constexpr int TT    = 16;
constexpr int ROWS  = 40;   // 4*8 + 8 halo
constexpr int C4    = 34;   // float4 slots per row = 136 cols
constexpr int LDSW  = 140;  // row pitch (floats): float4-aligned rows, 2-way-max bank spread
constexpr int RSPLIT = 24;  // rows in stage P1a

typedef float fvec4 __attribute__((ext_vector_type(4)));

__device__ __forceinline__ float4 compute_slot(
    const float* __restrict__ inp, const float* __restrict__ wlds,
    int h0, int w0, int r, int c4)
{
    const int h = h0 + r;
    const int w = w0 + c4 * 4;
    float4 acc = make_float4(0.f, 0.f, 0.f, 0.f);
    if (h < 256 && w < 256) {
        const float* wrow = &wlds[(h & 7) * 8 + (w & 7)];
        const float* gp   = inp + h * 256 + w;
#pragma unroll
        for (int t = 0; t < TT; ++t) {
            const float4 v  = *reinterpret_cast<const float4*>(gp + t * 65536);
            const float4 wv = *reinterpret_cast<const float4*>(wrow + t * 64);
            acc.x += v.x * wv.x;
            acc.y += v.y * wv.y;
            acc.z += v.z * wv.z;
            acc.w += v.w * wv.w;
        }
    }
    return acc;
}

__device__ __forceinline__ void store_nt(float* p, float a, float b, float c, float d)
{
    fvec4 v;
    v.x = a; v.y = b; v.z = c; v.w = d;
    __builtin_nontemporal_store(v, reinterpret_cast<fvec4*>(p));
}

__global__ __launch_bounds__(512, 4) void meas_kernel(
    const float* __restrict__ in, const float* __restrict__ wt,
    float* __restrict__ out)
{
    __shared__ float tile[ROWS * LDSW];
    __shared__ float wlds[TT * 64];

    const int tid = threadIdx.x;
    for (int idx = tid; idx < TT * 64; idx += 512) wlds[idx] = wt[idx];

    // XCD-aware swizzle: 512 blocks, 8 XCDs -> 64 logical blocks (one batch image) per XCD.
    const int bid = (blockIdx.x & 7) * 64 + (blockIdx.x >> 3);
    const int jg = bid & 1;
    const int ig = (bid >> 1) & 7;
    const int s  = (bid >> 4) & 3;
    const int b  = bid >> 6;

    const int i0 = ig * 4;
    const int j0 = jg * 16;
    const int h0 = i0 * 8;
    const int w0 = j0 * 8;

    const float* __restrict__ inp = in + (size_t)(b * 4 + s) * TT * 65536;

    // store-phase lane mapping: k = 4*lane + jj : p = 4*(lane%4) + jj, q = lane/4
    const int wave = tid >> 6;     // 0..7
    const int lane = tid & 63;
    const int p0 = (lane & 3) * 4;
    const int q  = lane >> 2;
    float* __restrict__ outb = out + ((size_t)b * 4096 + (size_t)s * 1024) * 256;

    __syncthreads();

    // ---- P1a: compute tile rows [0, 24) ----
    for (int slot = tid; slot < RSPLIT * C4; slot += 512) {
        const int r  = slot / C4;
        const int c4 = slot - r * C4;
        float4 acc = compute_slot(inp, wlds, h0, w0, r, c4);
        *reinterpret_cast<float4*>(&tile[r * LDSW + c4 * 4]) = acc;
    }

    __syncthreads();

    // ---- P1b: rows [24, 40) into registers (loads in flight during S01) ----
    constexpr int NB = (ROWS - RSPLIT) * C4;   // 544
    float4 acc0, acc1;
    int r0 = 0, c40 = 0, r1 = 0, c41 = 0;
    {
        const int slot = tid;                  // tid < 544 always (512 threads)
        r0  = RSPLIT + slot / C4;
        c40 = slot - (slot / C4) * C4;
        acc0 = compute_slot(inp, wlds, h0, w0, r0, c40);
    }
    const bool has1 = tid < (NB - 512);        // 32 threads
    if (has1) {
        const int slot = tid + 512;
        r1  = RSPLIT + slot / C4;
        c41 = slot - (slot / C4) * C4;
        acc1 = compute_slot(inp, wlds, h0, w0, r1, c41);
    }

    // ---- S01: store windows di = 0,1 (LDS rows 0..23) ----
    for (int widx = wave; widx < 32; widx += 8) {
        const int di = widx >> 4;   // 0..1
        const int dj = widx & 15;
        const float* src = &tile[(di * 8 + p0) * LDSW + dj * 8 + q];
        const int n = (i0 + di) * 32 + (j0 + dj);
        store_nt(outb + (size_t)n * 256 + lane * 4,
                 src[0 * LDSW], src[1 * LDSW], src[2 * LDSW], src[3 * LDSW]);
    }

    // ---- commit P1b rows to LDS ----
    *reinterpret_cast<float4*>(&tile[r0 * LDSW + c40 * 4]) = acc0;
    if (has1)
        *reinterpret_cast<float4*>(&tile[r1 * LDSW + c41 * 4]) = acc1;

    __syncthreads();

    // ---- S23: store windows di = 2,3 ----
    for (int widx = 32 + wave; widx < 64; widx += 8) {
        const int di = widx >> 4;   // 2..3
        const int dj = widx & 15;
        const float* src = &tile[(di * 8 + p0) * LDSW + dj * 8 + q];
        const int n = (i0 + di) * 32 + (j0 + dj);
        store_nt(outb + (size_t)n * 256 + lane * 4,
                 src[0 * LDSW], src[1 * LDSW], src[2 * LDSW], src[3 * LDSW]);
    }
}

} // namespace

extern "C" void kernel_launch(void* const* d_in, const int* in_sizes, int n_in,
                              void* d_out, int out_size, void* d_ws, size_t ws_size,
                              hipStream_t stream) {
    const float* in = (const float*)d_in[0];
    const float* wt = (const float*)d_in[1];
    float* out      = (float*)d_out;
    hipLaunchKernelGGL(meas_kernel, dim3(512), dim3(512), 0, stream, in, wt, out);
}